// Round 9
// baseline (237.064 us; speedup 1.0000x reference)
//
#include <hip/hip_runtime.h>
#include <math.h>

// Sizes (fixed by the reference)
#define Zc   4
#define Nc   128
#define EMBc 16
#define L0c  32
#define MLPHc 64
#define GEOc 64
#define NBc  32
#define NHc  128
#define Cc   128   // MLPH + GEO
#define SLc  64    // split-K slices in gemm3

typedef float  f32x4  __attribute__((ext_vector_type(4)));
typedef short  bf16x8 __attribute__((ext_vector_type(8)));

union FragU {
    bf16x8 v;
    unsigned short u[8];
    uint2 q2[2];
};

// accurate softplus-shifted (fp32 chain)
__device__ __forceinline__ float sp5(float x){
    float y = 5.0f * x;
    float t = fabsf(y);
    return (fmaxf(y, 0.0f) + log1pf(__expf(-t))) * 0.2f;
}
// post-accumulator activation: input y = 5*preact (5 folded into weights)
__device__ __forceinline__ float ssp5_post(float y){
    float e = __expf(-fabsf(y));
    float u = fmaxf(y, 0.0f) + __logf(1.0f + e);
    return fmaf(0.2f, u, -0.13862943611198906f);
}

// packed f32->bf16 (RNE); low 16 bits = src a, high = src b
__device__ __forceinline__ unsigned int cvtpk_bf16(float a, float b){
    unsigned int r;
    asm("v_cvt_pk_bf16_f32 %0, %1, %2" : "=v"(r) : "v"(a), "v"(b));
    return r;
}
__device__ __forceinline__ unsigned short f2bf(float f){   // packw only
    unsigned int u = __float_as_uint(f);
    unsigned int r = (u + 0x7FFFu + ((u >> 16) & 1u)) >> 16;
    return (unsigned short)r;
}

// shared k-map for MFMA fragments (A-gen and B-pack must agree)
__device__ __forceinline__ int kmap(int l, int e){
    return 4*((l >> 4) & 3) + (e & 3) + 16*(e >> 2);
}

// ---------------------------------------------------------------------------
// Merged setup: blocks 0..127 = pointnet (4 atoms each); 128..367 = packw;
// 368 = zero d_out.  All branches block-uniform.
__global__ __launch_bounds__(256) void k_init(
    const float* __restrict__ geom, const float* __restrict__ mask,
    const float* __restrict__ pw0, const float* __restrict__ pb0,
    const float* __restrict__ w1a, const float* __restrict__ b1a,
    const float* __restrict__ w1b, const float* __restrict__ b1b,
    const float* __restrict__ w2a, const float* __restrict__ b2a,
    const float* __restrict__ w2b, const float* __restrict__ b2b,
    const int*   __restrict__ features, const float* __restrict__ emb,
    const float* __restrict__ w00, const float* __restrict__ w10,
    const float* __restrict__ w01, const float* __restrict__ w11,
    const float* __restrict__ w02, const float* __restrict__ w12,
    float* __restrict__ geo_pn, float* __restrict__ f0,
    unsigned short* __restrict__ packs, float* __restrict__ outz)
{
    __shared__ float cur[4][GEOc];
    __shared__ float tmp[4][GEOc];
    int bx = blockIdx.x;
    int t  = threadIdx.x;
    if (bx < 128){
        int g  = t >> 6;          // atom group 0..3 (one wave each)
        int c  = t & 63;
        int zn = bx*4 + g;
        float gx = geom[zn*3+0], gy = geom[zn*3+1], gz = geom[zn*3+2];
        float v = fmaf(gx, pw0[0*GEOc+c], fmaf(gy, pw0[1*GEOc+c], fmaf(gz, pw0[2*GEOc+c], pb0[c])));
        const float* WA[2] = {w1a, w2a}; const float* BA[2] = {b1a, b2a};
        const float* WB[2] = {w1b, w2b}; const float* BB[2] = {b1b, b2b};
        #pragma unroll
        for (int blk = 0; blk < 2; blk++){
            cur[g][c] = v;
            __syncthreads();
            float s = BA[blk][c];
            for (int k = 0; k < GEOc; k++) s = fmaf(fmaxf(cur[g][k], 0.0f), WA[blk][k*GEOc+c], s);
            tmp[g][c] = s;
            __syncthreads();
            float s2 = BB[blk][c];
            for (int k = 0; k < GEOc; k++) s2 = fmaf(fmaxf(tmp[g][k], 0.0f), WB[blk][k*GEOc+c], s2);
            v = v + s2;
            __syncthreads();
        }
        geo_pn[zn*GEOc + c] = v * mask[zn];
        if (c < EMBc){
            int fi = features[zn];
            f0[zn*EMBc + c] = emb[fi*EMBc + c] * mask[zn] * 0.0022038655607334227f;
        }
    } else if (bx < 368){
        int j = bx - 128;
        int layer = j / 80;
        int sub = j % 80;
        const float* w0s = (layer == 0) ? w00 : (layer == 1) ? w01 : w02;
        const float* w1s = (layer == 0) ? w10 : (layer == 1) ? w11 : w12;
        unsigned short* p0 = packs + layer*4096;
        unsigned short* p1 = packs + 12288 + layer*16384;
        int idx = sub*256 + t;
        if (idx < 4096){
            int t8 = idx >> 9, l = (idx >> 3) & 63, e = idx & 7;
            int k = kmap(l, e);
            int n = (t8 << 4) + (l & 15);
            p0[idx] = f2bf(w0s[k*NHc + n] * 0.8838834764831844f);    // 5/sqrt(32)
        } else {
            int jj = idx - 4096;
            int fid = jj >> 9, l = (jj >> 3) & 63, e = jj & 7;
            int kk = fid >> 3, t8 = fid & 7;
            int k = 32*kk + kmap(l, e);
            int n = 16*t8 + (l & 15);
            p1[jj] = f2bf(w1s[k*NHc + n] * 0.4419417382415922f);     // 5/sqrt(128)
        }
    } else {
        for (int i = t; i < Zc*2*Cc; i += 256) outz[i] = 0.0f;
    }
}

// ---------------------------------------------------------------------------
// gt[z][i][m*Nc + b] = sum_j w2[m*DOUT+i, j] * f[zb,j]  (bf16; K-order m*Nc+b
// matches pairmlp's h2 [a][n][b] layout).  Thread owns (m,i) x 8 contig b's.
template<int DIN, int DOUT>
__global__ __launch_bounds__(256) void k_gmat(
    const float* __restrict__ f, const float* __restrict__ w2,
    unsigned short* __restrict__ gt)
{
    __shared__ float fsh[8][DIN];
    int t   = threadIdx.x;
    int zb0 = blockIdx.x * 8;
    if (t < 8*DIN){
        int r = t / DIN, j = t % DIN;
        fsh[r][j] = f[(zb0 + r)*DIN + j];
    }
    __syncthreads();
    int mi = blockIdx.y * 256 + t;      // = i*NH + m
    int m_ = mi & (NHc-1);
    int i_ = mi >> 7;
    const float* wrow = w2 + (size_t)(m_*DOUT + i_) * DIN;
    float s[8];
    #pragma unroll
    for (int r = 0; r < 8; r++) s[r] = 0.0f;
    #pragma unroll
    for (int j4 = 0; j4 < DIN/4; j4++){
        float4 w = *reinterpret_cast<const float4*>(&wrow[j4*4]);
        #pragma unroll
        for (int q = 0; q < 4; q++){
            float wv = reinterpret_cast<const float*>(&w)[q];
            int j = j4*4 + q;
            #pragma unroll
            for (int r = 0; r < 8; r++)
                s[r] = fmaf(fsh[r][j], wv, s[r]);
        }
    }
    int z   = zb0 >> 7;
    int b0p = zb0 & (Nc-1);
    uint4 pk;
    pk.x = cvtpk_bf16(s[0], s[1]); pk.y = cvtpk_bf16(s[2], s[3]);
    pk.z = cvtpk_bf16(s[4], s[5]); pk.w = cvtpk_bf16(s[6], s[7]);
    *reinterpret_cast<uint4*>(gt + ((size_t)z*DOUT + i_)*(Nc*NHc) + m_*Nc + b0p) = pk;
}

// Fused previous-layer epilogue + gmat (part re-reads are L2-hot).
template<int DIN, int DOUT>
__global__ __launch_bounds__(256) void k_egmat(
    const float* __restrict__ part, const float* __restrict__ mask,
    const float* __restrict__ w2, unsigned short* __restrict__ gt)
{
    __shared__ float fsh[8][DIN];
    int t   = threadIdx.x;
    int zb0 = blockIdx.x * 8;
    for (int idx = t; idx < 8*DIN; idx += 256){
        int r = idx / DIN, j = idx % DIN;
        int zb = zb0 + r;
        float s = 0.0f;
        #pragma unroll
        for (int sl = 0; sl < SLc; sl++)
            s += part[(size_t)sl*(Zc*Nc*DIN) + zb*DIN + j];
        float m = mask[zb];
        fsh[r][j] = sp5(s) * m * m * 0.0022038655607334227f;
    }
    __syncthreads();
    int mi = blockIdx.y * 256 + t;
    int m_ = mi & (NHc-1);
    int i_ = mi >> 7;
    const float* wrow = w2 + (size_t)(m_*DOUT + i_) * DIN;
    float s[8];
    #pragma unroll
    for (int r = 0; r < 8; r++) s[r] = 0.0f;
    #pragma unroll
    for (int j4 = 0; j4 < DIN/4; j4++){
        float4 w = *reinterpret_cast<const float4*>(&wrow[j4*4]);
        #pragma unroll
        for (int q = 0; q < 4; q++){
            float wv = reinterpret_cast<const float*>(&w)[q];
            int j = j4*4 + q;
            #pragma unroll
            for (int r = 0; r < 8; r++)
                s[r] = fmaf(fsh[r][j], wv, s[r]);
        }
    }
    int z   = zb0 >> 7;
    int b0p = zb0 & (Nc-1);
    uint4 pk;
    pk.x = cvtpk_bf16(s[0], s[1]); pk.y = cvtpk_bf16(s[2], s[3]);
    pk.z = cvtpk_bf16(s[4], s[5]); pk.w = cvtpk_bf16(s[6], s[7]);
    *reinterpret_cast<uint4*>(gt + ((size_t)z*DOUT + i_)*(Nc*NHc) + m_*Nc + b0p) = pk;
}

// ---------------------------------------------------------------------------
// MFMA pair-MLP, 3 layers per block (basis amortized), symmetry-halved.
// h2 layout: [a][n][b] (K-order n*Nc+b) -> rg-quad (consecutive b) packs
// into one uint2 store.  Mirror writes h2[b][n][a] scalar, b>a only.
__global__ __launch_bounds__(256, 2) void k_pairmlp(
    const float* __restrict__ geom,
    const unsigned short* __restrict__ packs,
    unsigned short* __restrict__ h2all)
{
    __shared__ unsigned short h1s[64*128];   // 16 KB, XOR-swizzled [m][k] bf16
    char* lb = (char*)h1s;
    int t   = threadIdx.x;
    int w   = t >> 6;
    int l   = t & 63;
    int g16 = l >> 4;
    int c   = l & 15;
    int p0  = blockIdx.x * 64;
    int z   = p0 >> 14;
    int a   = (p0 >> 7) & 127;
    int b0  = p0 & 127;

    if (b0 + 16*w + 15 < a) return;   // fully below diagonal: mirrors cover it

    int bp = b0 + 16*w + c;
    float ax = geom[(z*Nc + a)*3 + 0];
    float ay = geom[(z*Nc + a)*3 + 1];
    float az = geom[(z*Nc + a)*3 + 2];
    float dx = geom[(z*Nc + bp)*3 + 0] - ax;
    float dy = geom[(z*Nc + bp)*3 + 1] - ay;
    float dz = geom[(z*Nc + bp)*3 + 2] - az;
    float rm = sqrtf(dx*dx + dy*dy + dz*dz);

    // basis A-fragment, computed once for all 3 layers
    FragU af;
    #pragma unroll
    for (int e = 0; e < 8; e++){
        int k = kmap(l, e);
        float x = fmaf(rm, 3.1f, -(float)k);   // (r - k*step)/step, step=10/31
        float v = 0.0f;
        if (fabsf(x) < 1.0f){ float cc = __cosf(1.57079632679f*x); v = cc*cc; }
        af.u[e] = (unsigned short)cvtpk_bf16(v, v);
    }

    size_t zbase = (size_t)z*Nc*Nc*NHc;
    int mrow  = 16*w + c;
    int sw    = (mrow & 7) << 4;
    int bprim = b0 + 16*w + 4*g16;
    bool mir0 = (bprim + 0) > a, mir1 = (bprim + 1) > a;
    bool mir2 = (bprim + 2) > a, mir3 = (bprim + 3) > a;

    for (int layer = 0; layer < 3; layer++){
        const unsigned short* wp0 = packs + layer*4096;
        const unsigned short* wp1 = packs + 12288 + layer*16384;
        unsigned short* h2 = h2all + (size_t)layer * (Zc*Nc*Nc*NHc);

        // phase 1: y1 = basis @ w0pack (5/sqrt32 folded)
        f32x4 acc[8];
        #pragma unroll
        for (int t8 = 0; t8 < 8; t8++) acc[t8] = (f32x4){0.f,0.f,0.f,0.f};
        #pragma unroll
        for (int t8 = 0; t8 < 8; t8++){
            bf16x8 bf = *reinterpret_cast<const bf16x8*>(wp0 + ((t8*64 + l) << 3));
            acc[t8] = __builtin_amdgcn_mfma_f32_16x16x32_bf16(af.v, bf, acc[t8], 0, 0, 0);
        }
        #pragma unroll
        for (int t8 = 0; t8 < 8; t8++){
            #pragma unroll
            for (int rg = 0; rg < 4; rg++){
                int m = 16*w + 4*g16 + rg;
                int n = 16*t8 + c;
                int off = ((m << 8) + (n << 1)) ^ ((m & 7) << 4);
                *(unsigned short*)(lb + off) = (unsigned short)cvtpk_bf16(ssp5_post(acc[t8][rg]), 0.0f);
            }
        }
        // no barrier: wave w wrote rows [16w,16w+16) and reads only those.

        // phase 2: y2 = h1 @ w1pack (5/sqrt128 folded)
        f32x4 acc2[8];
        #pragma unroll
        for (int t8 = 0; t8 < 8; t8++) acc2[t8] = (f32x4){0.f,0.f,0.f,0.f};
        #pragma unroll
        for (int kk = 0; kk < 4; kk++){
            int ob = (mrow << 8) + (kk << 6) + (g16 << 3);
            FragU a2;
            a2.q2[0] = *(const uint2*)(lb + (ob ^ sw));
            a2.q2[1] = *(const uint2*)(lb + ((ob + 32) ^ sw));
            #pragma unroll
            for (int t8 = 0; t8 < 8; t8++){
                bf16x8 bf = *reinterpret_cast<const bf16x8*>(wp1 + (((kk*8 + t8)*64 + l) << 3));
                acc2[t8] = __builtin_amdgcn_mfma_f32_16x16x32_bf16(a2.v, bf, acc2[t8], 0, 0, 0);
            }
        }
        // stores: primary packed uint2 per t8; mirror scalar (b>a)
        #pragma unroll
        for (int t8 = 0; t8 < 8; t8++){
            int n = 16*t8 + c;
            unsigned int d0 = cvtpk_bf16(ssp5_post(acc2[t8][0]), ssp5_post(acc2[t8][1]));
            unsigned int d1 = cvtpk_bf16(ssp5_post(acc2[t8][2]), ssp5_post(acc2[t8][3]));
            uint2 pr; pr.x = d0; pr.y = d1;
            *reinterpret_cast<uint2*>(h2 + zbase + ((size_t)a*NHc + n)*Nc + bprim) = pr;
            if (mir0) h2[zbase + ((size_t)(bprim+0)*NHc + n)*Nc + a] = (unsigned short)(d0 & 0xffffu);
            if (mir1) h2[zbase + ((size_t)(bprim+1)*NHc + n)*Nc + a] = (unsigned short)(d0 >> 16);
            if (mir2) h2[zbase + ((size_t)(bprim+2)*NHc + n)*Nc + a] = (unsigned short)(d1 & 0xffffu);
            if (mir3) h2[zbase + ((size_t)(bprim+3)*NHc + n)*Nc + a] = (unsigned short)(d1 >> 16);
        }
    }
}

// ---------------------------------------------------------------------------
// MFMA gemm3: partial[s][z][a][i] = sum_{k' in slice s} h2[z,a,k']*gt[z,i,k']
// (K-order agnostic).  grid = (64 k-slices, 2 a-tiles of 64, Z); 4 waves.
template<int DOUT>
__global__ __launch_bounds__(256) void k_gemm3m(
    const unsigned short* __restrict__ h2, const unsigned short* __restrict__ gt,
    float* __restrict__ partial)
{
    __shared__ unsigned short Ash[64*256];     // 32 KB swizzled [r][k]
    __shared__ unsigned short Bsh[DOUT*256];   // 32/16 KB swizzled [c][k]
    int t = threadIdx.x;
    int w = t >> 6, l = t & 63;
    int g16 = l >> 4, c16 = l & 15;
    int s  = blockIdx.x;        // 0..63 k-slice (256 k' each)
    int at = blockIdx.y;        // 0..1
    int z  = blockIdx.z;
    int a0 = at*64;
    int k0 = s*256;

    {
        const unsigned short* src = h2 + ((size_t)(z*Nc + a0))*(Nc*NHc) + k0;
        #pragma unroll
        for (int it = 0; it < 8; it++){
            int idx = it*256 + t;
            int r = idx >> 5, c8 = idx & 31;
            uint4 v = *reinterpret_cast<const uint4*>(src + (size_t)r*(Nc*NHc) + c8*8);
            int byte = (r*512 + c8*16) ^ ((r & 7) << 4);
            *reinterpret_cast<uint4*>((char*)Ash + byte) = v;
        }
    }
    {
        const unsigned short* src = gt + ((size_t)z*DOUT)*(Nc*NHc) + k0;
        #pragma unroll
        for (int it = 0; it < DOUT/8; it++){
            int idx = it*256 + t;
            int r = idx >> 5, c8 = idx & 31;
            uint4 v = *reinterpret_cast<const uint4*>(src + (size_t)r*(Nc*NHc) + c8*8);
            int byte = (r*512 + c8*16) ^ ((r & 7) << 4);
            *reinterpret_cast<uint4*>((char*)Bsh + byte) = v;
        }
    }
    __syncthreads();

    constexpr int NT = DOUT/16;
    f32x4 acc[NT];
    #pragma unroll
    for (int nt = 0; nt < NT; nt++) acc[nt] = (f32x4){0.f,0.f,0.f,0.f};
    char* Ab = (char*)Ash; char* Bb = (char*)Bsh;
    int ar  = 16*w + c16;
    int asw = (ar & 7) << 4;
    #pragma unroll
    for (int ks = 0; ks < 8; ks++){
        FragU afr;
        int abyte = ar*512 + ks*64 + g16*8;
        afr.q2[0] = *(const uint2*)(Ab + (abyte ^ asw));
        afr.q2[1] = *(const uint2*)(Ab + ((abyte + 32) ^ asw));
        #pragma unroll
        for (int nt = 0; nt < NT; nt++){
            int br  = nt*16 + c16;
            int bsw = (br & 7) << 4;
            int bbyte = br*512 + ks*64 + g16*8;
            FragU bfr;
            bfr.q2[0] = *(const uint2*)(Bb + (bbyte ^ bsw));
            bfr.q2[1] = *(const uint2*)(Bb + ((bbyte + 32) ^ bsw));
            acc[nt] = __builtin_amdgcn_mfma_f32_16x16x32_bf16(afr.v, bfr.v, acc[nt], 0, 0, 0);
        }
    }
    #pragma unroll
    for (int nt = 0; nt < NT; nt++){
        #pragma unroll
        for (int rg = 0; rg < 4; rg++){
            int a = a0 + 16*w + 4*g16 + rg;
            int i = nt*16 + c16;
            partial[(((size_t)s*Zc + z)*Nc + a)*DOUT + i] = acc[nt][rg];
        }
    }
}

// ---------------------------------------------------------------------------
// Fused tail: layer-2 epilogue -> x1 -> bn1+leaky -> x2 -> bn2+leaky ->
// masked atomic sum into d_out (zeroed by k_init).  grid = N blocks.
__global__ __launch_bounds__(256) void k_tail(
    const float* __restrict__ part, const float* __restrict__ mask,
    const float* __restrict__ geo_pn,
    const float* __restrict__ e1w, const float* __restrict__ e1b,
    const float* __restrict__ g1, const float* __restrict__ b1,
    const float* __restrict__ e2w, const float* __restrict__ e2b,
    const float* __restrict__ g2, const float* __restrict__ b2,
    float* __restrict__ outp)
{
    int n = blockIdx.x;
    int t = threadIdx.x;
    __shared__ float feat[Zc][Cc];
    __shared__ float xln[Zc][Cc];
    __shared__ float r1[4], r2[4];

    {
        int z = t >> 6, i = t & 63;
        float s = 0.0f;
        #pragma unroll
        for (int sl = 0; sl < SLc; sl++)
            s += part[((size_t)sl*Zc*Nc + z*Nc + n)*MLPHc + i];
        float m = mask[z*Nc + n];
        feat[z][i] = sp5(s) * m;
        feat[z][MLPHc + i] = geo_pn[(z*Nc + n)*GEOc + i];
    }
    __syncthreads();

    int c  = t & 127;
    int zh = t >> 7;
    float x1v[2];
    float sum = 0.0f, sq = 0.0f;
    #pragma unroll
    for (int q = 0; q < 2; q++){
        int z = zh*2 + q;
        float s = e1b[c];
        for (int k = 0; k < Cc; k++) s = fmaf(feat[z][k], e1w[k*Cc + c], s);
        x1v[q] = s; sum += s; sq = fmaf(s, s, sq);
    }
    #pragma unroll
    for (int off = 32; off > 0; off >>= 1){
        sum += __shfl_down(sum, off);
        sq  += __shfl_down(sq,  off);
    }
    if ((t & 63) == 0){ r1[t >> 6] = sum; r2[t >> 6] = sq; }
    __syncthreads();
    {
        float tot  = r1[0]+r1[1]+r1[2]+r1[3];
        float totq = r2[0]+r2[1]+r2[2]+r2[3];
        float mu   = tot * (1.0f/512.0f);
        float var  = totq * (1.0f/512.0f) - mu*mu;
        float rstd = rsqrtf(var + 1e-5f);
        float ga = g1[n], be = b1[n];
        #pragma unroll
        for (int q = 0; q < 2; q++){
            float v = (x1v[q] - mu) * rstd * ga + be;
            xln[zh*2 + q][c] = v > 0.0f ? v : 0.2f*v;
        }
    }
    __syncthreads();

    float x2v[4];
    sum = 0.0f; sq = 0.0f;
    #pragma unroll
    for (int z = 0; z < Zc; z++){
        float s = e2b[t];
        for (int k = 0; k < Cc; k++) s = fmaf(xln[z][k], e2w[k*2*Cc + t], s);
        x2v[z] = s; sum += s; sq = fmaf(s, s, sq);
    }
    #pragma unroll
    for (int off = 32; off > 0; off >>= 1){
        sum += __shfl_down(sum, off);
        sq  += __shfl_down(sq,  off);
    }
    if ((t & 63) == 0){ r1[t >> 6] = sum; r2[t >> 6] = sq; }
    __syncthreads();
    {
        float tot  = r1[0]+r1[1]+r1[2]+r1[3];
        float totq = r2[0]+r2[1]+r2[2]+r2[3];
        float mu   = tot * (1.0f/1024.0f);
        float var  = totq * (1.0f/1024.0f) - mu*mu;
        float rstd = rsqrtf(var + 1e-5f);
        float ga = g2[n], be = b2[n];
        #pragma unroll
        for (int z = 0; z < Zc; z++){
            float v = (x2v[z] - mu) * rstd * ga + be;
            v = v > 0.0f ? v : 0.2f*v;
            atomicAdd(&outp[z*2*Cc + t], v * mask[z*Nc + n]);
        }
    }
}

// ---------------------------------------------------------------------------
extern "C" void kernel_launch(void* const* d_in, const int* in_sizes, int n_in,
                              void* d_out, int out_size, void* d_ws, size_t ws_size,
                              hipStream_t stream)
{
    const int*   features = (const int*)  d_in[0];
    const float* geom     = (const float*)d_in[1];
    const float* mask     = (const float*)d_in[2];
    const float* emb      = (const float*)d_in[3];
    const float* rw[3][3] = {
        {(const float*)d_in[4],  (const float*)d_in[5],  (const float*)d_in[6]},
        {(const float*)d_in[7],  (const float*)d_in[8],  (const float*)d_in[9]},
        {(const float*)d_in[10], (const float*)d_in[11], (const float*)d_in[12]}};
    const float* pw0 = (const float*)d_in[13]; const float* pb0 = (const float*)d_in[14];
    const float* w1a = (const float*)d_in[15]; const float* b1a = (const float*)d_in[16];
    const float* w1b = (const float*)d_in[17]; const float* b1b = (const float*)d_in[18];
    const float* w2a = (const float*)d_in[19]; const float* b2a = (const float*)d_in[20];
    const float* w2b = (const float*)d_in[21]; const float* b2b = (const float*)d_in[22];
    const float* e1w = (const float*)d_in[23]; const float* e1b = (const float*)d_in[24];
    const float* bn1g= (const float*)d_in[25]; const float* bn1b= (const float*)d_in[26];
    const float* e2w = (const float*)d_in[27]; const float* e2b = (const float*)d_in[28];
    const float* bn2g= (const float*)d_in[29]; const float* bn2b= (const float*)d_in[30];

    // workspace layout (float units from base)
    float* ws = (float*)d_ws;
    unsigned short* h2buf = (unsigned short*)ws;               // 3*Z*N*N*NH ushort
    unsigned short* gt    = (unsigned short*)(ws + 12582912);  // Z*64*16384 ushort
    float* part   = ws + 12582912 + 2097152;                   // SL*Z*N*64 = 2097152
    float* f0     = part + 2097152;                            // Z*N*EMB   = 8192
    float* geo_pn = f0 + 8192;                                 // Z*N*64    = 32768
    unsigned short* packs = (unsigned short*)(geo_pn + 32768); // 61440 ushorts
    (void)ws_size; (void)in_sizes; (void)n_in; (void)out_size;

    const size_t H2L = (size_t)Zc*Nc*Nc*NHc;                   // per-layer h2 elements

    // merged pointnet + packw + d_out zeroing
    k_init<<<369, 256, 0, stream>>>(geom, mask, pw0, pb0, w1a, b1a, w1b, b1b,
                                    w2a, b2a, w2b, b2b, features, emb,
                                    rw[0][0], rw[0][1], rw[1][0], rw[1][1],
                                    rw[2][0], rw[2][1],
                                    geo_pn, f0, packs, (float*)d_out);
    // all 3 layers' pair-MLPs, one launch, 3 layers per block
    k_pairmlp<<<Zc*Nc*Nc/64, 256, 0, stream>>>(geom, packs, h2buf);

    // layer 0: din=16(EMB), dout=32
    k_gmat<16,32><<<dim3(Zc*Nc/8, (NHc*32)/256), 256, 0, stream>>>(f0, rw[0][2], gt);
    k_gemm3m<32><<<dim3(SLc,2,Zc), 256, 0, stream>>>(h2buf, gt, part);
    // layer 1: din=32, dout=32
    k_egmat<32,32><<<dim3(Zc*Nc/8, (NHc*32)/256), 256, 0, stream>>>(part, mask, rw[1][2], gt);
    k_gemm3m<32><<<dim3(SLc,2,Zc), 256, 0, stream>>>(h2buf + H2L, gt, part);
    // layer 2: din=32, dout=64
    k_egmat<32,64><<<dim3(Zc*Nc/8, (NHc*64)/256), 256, 0, stream>>>(part, mask, rw[2][2], gt);
    k_gemm3m<64><<<dim3(SLc,2,Zc), 256, 0, stream>>>(h2buf + 2*H2L, gt, part);

    // fused tail (epilogue2+x1+bn1+x2+bn2+masked atomic sum)
    k_tail<<<Nc, 256, 0, stream>>>(part, mask, geo_pn, e1w, e1b, bn1g, bn1b,
                                   e2w, e2b, bn2g, bn2b, (float*)d_out);
}

// Round 10
// 152.258 us; speedup vs baseline: 1.5570x; 1.5570x over previous
//
#include <hip/hip_runtime.h>
#include <math.h>

// Sizes (fixed by the reference)
#define Zc   4
#define Nc   128
#define EMBc 16
#define L0c  32
#define MLPHc 64
#define GEOc 64
#define NBc  32
#define NHc  128
#define Cc   128   // MLPH + GEO
#define SLc  64    // split-K slices in gemm3

typedef float  f32x4  __attribute__((ext_vector_type(4)));
typedef short  bf16x8 __attribute__((ext_vector_type(8)));

union FragU {
    bf16x8 v;
    unsigned short u[8];
    uint2 q2[2];
};

// accurate softplus-shifted (fp32 chain)
__device__ __forceinline__ float sp5(float x){
    float y = 5.0f * x;
    float t = fabsf(y);
    return (fmaxf(y, 0.0f) + log1pf(__expf(-t))) * 0.2f;
}
// post-accumulator activation: input y = 5*preact (5 folded into weights)
__device__ __forceinline__ float ssp5_post(float y){
    float e = __expf(-fabsf(y));
    float u = fmaxf(y, 0.0f) + __logf(1.0f + e);
    return fmaf(0.2f, u, -0.13862943611198906f);
}

// packed f32->bf16 (RNE); low 16 bits = src a, high = src b
__device__ __forceinline__ unsigned int cvtpk_bf16(float a, float b){
    unsigned int r;
    asm("v_cvt_pk_bf16_f32 %0, %1, %2" : "=v"(r) : "v"(a), "v"(b));
    return r;
}
__device__ __forceinline__ unsigned short f2bf(float f){   // packw only
    unsigned int u = __float_as_uint(f);
    unsigned int r = (u + 0x7FFFu + ((u >> 16) & 1u)) >> 16;
    return (unsigned short)r;
}

// shared k-map for MFMA fragments (A-gen and B-pack must agree)
__device__ __forceinline__ int kmap(int l, int e){
    return 4*((l >> 4) & 3) + (e & 3) + 16*(e >> 2);
}

// ---------------------------------------------------------------------------
// Merged setup: blocks 0..127 = pointnet (4 atoms each); 128..367 = packw;
// 368 = zero d_out.  All branches block-uniform.
__global__ __launch_bounds__(256) void k_init(
    const float* __restrict__ geom, const float* __restrict__ mask,
    const float* __restrict__ pw0, const float* __restrict__ pb0,
    const float* __restrict__ w1a, const float* __restrict__ b1a,
    const float* __restrict__ w1b, const float* __restrict__ b1b,
    const float* __restrict__ w2a, const float* __restrict__ b2a,
    const float* __restrict__ w2b, const float* __restrict__ b2b,
    const int*   __restrict__ features, const float* __restrict__ emb,
    const float* __restrict__ w00, const float* __restrict__ w10,
    const float* __restrict__ w01, const float* __restrict__ w11,
    const float* __restrict__ w02, const float* __restrict__ w12,
    float* __restrict__ geo_pn, float* __restrict__ f0,
    unsigned short* __restrict__ packs, float* __restrict__ outz)
{
    __shared__ float cur[4][GEOc];
    __shared__ float tmp[4][GEOc];
    int bx = blockIdx.x;
    int t  = threadIdx.x;
    if (bx < 128){
        int g  = t >> 6;          // atom group 0..3 (one wave each)
        int c  = t & 63;
        int zn = bx*4 + g;
        float gx = geom[zn*3+0], gy = geom[zn*3+1], gz = geom[zn*3+2];
        float v = fmaf(gx, pw0[0*GEOc+c], fmaf(gy, pw0[1*GEOc+c], fmaf(gz, pw0[2*GEOc+c], pb0[c])));
        const float* WA[2] = {w1a, w2a}; const float* BA[2] = {b1a, b2a};
        const float* WB[2] = {w1b, w2b}; const float* BB[2] = {b1b, b2b};
        #pragma unroll
        for (int blk = 0; blk < 2; blk++){
            cur[g][c] = v;
            __syncthreads();
            float s = BA[blk][c];
            for (int k = 0; k < GEOc; k++) s = fmaf(fmaxf(cur[g][k], 0.0f), WA[blk][k*GEOc+c], s);
            tmp[g][c] = s;
            __syncthreads();
            float s2 = BB[blk][c];
            for (int k = 0; k < GEOc; k++) s2 = fmaf(fmaxf(tmp[g][k], 0.0f), WB[blk][k*GEOc+c], s2);
            v = v + s2;
            __syncthreads();
        }
        geo_pn[zn*GEOc + c] = v * mask[zn];
        if (c < EMBc){
            int fi = features[zn];
            f0[zn*EMBc + c] = emb[fi*EMBc + c] * mask[zn] * 0.0022038655607334227f;
        }
    } else if (bx < 368){
        int j = bx - 128;
        int layer = j / 80;
        int sub = j % 80;
        const float* w0s = (layer == 0) ? w00 : (layer == 1) ? w01 : w02;
        const float* w1s = (layer == 0) ? w10 : (layer == 1) ? w11 : w12;
        unsigned short* p0 = packs + layer*4096;
        unsigned short* p1 = packs + 12288 + layer*16384;
        int idx = sub*256 + t;
        if (idx < 4096){
            int t8 = idx >> 9, l = (idx >> 3) & 63, e = idx & 7;
            int k = kmap(l, e);
            int n = (t8 << 4) + (l & 15);
            p0[idx] = f2bf(w0s[k*NHc + n] * 0.8838834764831844f);    // 5/sqrt(32)
        } else {
            int jj = idx - 4096;
            int fid = jj >> 9, l = (jj >> 3) & 63, e = jj & 7;
            int kk = fid >> 3, t8 = fid & 7;
            int k = 32*kk + kmap(l, e);
            int n = 16*t8 + (l & 15);
            p1[jj] = f2bf(w1s[k*NHc + n] * 0.4419417382415922f);     // 5/sqrt(128)
        }
    } else {
        for (int i = t; i < Zc*2*Cc; i += 256) outz[i] = 0.0f;
    }
}

// ---------------------------------------------------------------------------
// gt[z][i][b*NH + m] = sum_j w2[m*DOUT+i, j] * f[zb,j]  (bf16, K-order b*NH+m,
// matching pairmlp's h2 [a][b][n]).  Lane-coalesced scalar stores (m fastest).
template<int DIN, int DOUT>
__global__ __launch_bounds__(256) void k_gmat(
    const float* __restrict__ f, const float* __restrict__ w2,
    unsigned short* __restrict__ gt)
{
    __shared__ float fsh[8][DIN];
    int t   = threadIdx.x;
    int zb0 = blockIdx.x * 8;
    if (t < 8*DIN){
        int r = t / DIN, j = t % DIN;
        fsh[r][j] = f[(zb0 + r)*DIN + j];
    }
    __syncthreads();
    int mi = blockIdx.y * 256 + t;      // = i*NH + m  (m fastest -> coalesced)
    int m_ = mi & (NHc-1);
    int i_ = mi >> 7;
    const float* wrow = w2 + (size_t)(m_*DOUT + i_) * DIN;
    float s[8];
    #pragma unroll
    for (int r = 0; r < 8; r++) s[r] = 0.0f;
    #pragma unroll
    for (int j4 = 0; j4 < DIN/4; j4++){
        float4 w = *reinterpret_cast<const float4*>(&wrow[j4*4]);
        #pragma unroll
        for (int q = 0; q < 4; q++){
            float wv = reinterpret_cast<const float*>(&w)[q];
            int j = j4*4 + q;
            #pragma unroll
            for (int r = 0; r < 8; r++)
                s[r] = fmaf(fsh[r][j], wv, s[r]);
        }
    }
    int z = zb0 >> 7;
    #pragma unroll
    for (int r = 0; r < 8; r++){
        int b = (zb0 + r) & (Nc-1);
        gt[((size_t)z*DOUT + i_)*(Nc*NHc) + b*NHc + m_] = (unsigned short)cvtpk_bf16(s[r], s[r]);
    }
}

// Fused previous-layer epilogue + gmat (part re-reads are L2-hot).
template<int DIN, int DOUT>
__global__ __launch_bounds__(256) void k_egmat(
    const float* __restrict__ part, const float* __restrict__ mask,
    const float* __restrict__ w2, unsigned short* __restrict__ gt)
{
    __shared__ float fsh[8][DIN];
    int t   = threadIdx.x;
    int zb0 = blockIdx.x * 8;
    for (int idx = t; idx < 8*DIN; idx += 256){
        int r = idx / DIN, j = idx % DIN;
        int zb = zb0 + r;
        float s = 0.0f;
        #pragma unroll
        for (int sl = 0; sl < SLc; sl++)
            s += part[(size_t)sl*(Zc*Nc*DIN) + zb*DIN + j];
        float m = mask[zb];
        fsh[r][j] = sp5(s) * m * m * 0.0022038655607334227f;
    }
    __syncthreads();
    int mi = blockIdx.y * 256 + t;
    int m_ = mi & (NHc-1);
    int i_ = mi >> 7;
    const float* wrow = w2 + (size_t)(m_*DOUT + i_) * DIN;
    float s[8];
    #pragma unroll
    for (int r = 0; r < 8; r++) s[r] = 0.0f;
    #pragma unroll
    for (int j4 = 0; j4 < DIN/4; j4++){
        float4 w = *reinterpret_cast<const float4*>(&wrow[j4*4]);
        #pragma unroll
        for (int q = 0; q < 4; q++){
            float wv = reinterpret_cast<const float*>(&w)[q];
            int j = j4*4 + q;
            #pragma unroll
            for (int r = 0; r < 8; r++)
                s[r] = fmaf(fsh[r][j], wv, s[r]);
        }
    }
    int z = zb0 >> 7;
    #pragma unroll
    for (int r = 0; r < 8; r++){
        int b = (zb0 + r) & (Nc-1);
        gt[((size_t)z*DOUT + i_)*(Nc*NHc) + b*NHc + m_] = (unsigned short)cvtpk_bf16(s[r], s[r]);
    }
}

// ---------------------------------------------------------------------------
// MFMA pair-MLP, symmetry-halved; h2 layout [z][a][b][n] (n fastest ->
// lane-coalesced stores, round-8 proven).  grid = (1024, 3 layers), 4 waves.
__global__ __launch_bounds__(256, 2) void k_pairmlp(
    const float* __restrict__ geom,
    const unsigned short* __restrict__ packs,
    unsigned short* __restrict__ h2all)
{
    __shared__ unsigned short h1s[64*128];   // 16 KB, XOR-swizzled [m][k] bf16
    char* lb = (char*)h1s;
    int t   = threadIdx.x;
    int w   = t >> 6;
    int l   = t & 63;
    int g16 = l >> 4;
    int c   = l & 15;
    int p0  = blockIdx.x * 64;
    int z   = p0 >> 14;
    int a   = (p0 >> 7) & 127;
    int b0  = p0 & 127;

    if (b0 + 16*w + 15 < a) return;   // fully below diagonal: mirrors cover it

    int layer = blockIdx.y;
    const unsigned short* wp0 = packs + layer*4096;
    const unsigned short* wp1 = packs + 12288 + layer*16384;
    unsigned short* h2 = h2all + (size_t)layer * (Zc*Nc*Nc*NHc);

    int bp = b0 + 16*w + c;
    float ax = geom[(z*Nc + a)*3 + 0];
    float ay = geom[(z*Nc + a)*3 + 1];
    float az = geom[(z*Nc + a)*3 + 2];
    float dx = geom[(z*Nc + bp)*3 + 0] - ax;
    float dy = geom[(z*Nc + bp)*3 + 1] - ay;
    float dz = geom[(z*Nc + bp)*3 + 2] - az;
    float rm = sqrtf(dx*dx + dy*dy + dz*dz);

    // basis A-fragment, computed in-register (K=32 covered by one frag)
    FragU af;
    #pragma unroll
    for (int e = 0; e < 8; e++){
        int k = kmap(l, e);
        float x = fmaf(rm, 3.1f, -(float)k);   // (r - k*step)/step, step=10/31
        float v = 0.0f;
        if (fabsf(x) < 1.0f){ float cc = __cosf(1.57079632679f*x); v = cc*cc; }
        af.u[e] = (unsigned short)cvtpk_bf16(v, v);
    }

    // phase 1: y1 = basis @ w0pack (5/sqrt32 folded)
    f32x4 acc[8];
    #pragma unroll
    for (int t8 = 0; t8 < 8; t8++) acc[t8] = (f32x4){0.f,0.f,0.f,0.f};
    #pragma unroll
    for (int t8 = 0; t8 < 8; t8++){
        bf16x8 bf = *reinterpret_cast<const bf16x8*>(wp0 + ((t8*64 + l) << 3));
        acc[t8] = __builtin_amdgcn_mfma_f32_16x16x32_bf16(af.v, bf, acc[t8], 0, 0, 0);
    }
    #pragma unroll
    for (int t8 = 0; t8 < 8; t8++){
        #pragma unroll
        for (int rg = 0; rg < 4; rg++){
            int m = 16*w + 4*g16 + rg;
            int n = 16*t8 + c;
            int off = ((m << 8) + (n << 1)) ^ ((m & 7) << 4);
            *(unsigned short*)(lb + off) = (unsigned short)cvtpk_bf16(ssp5_post(acc[t8][rg]), 0.0f);
        }
    }
    // no barrier: wave w wrote rows [16w,16w+16) and reads only those.

    // phase 2: y2 = h1 @ w1pack (5/sqrt128 folded)
    f32x4 acc2[8];
    #pragma unroll
    for (int t8 = 0; t8 < 8; t8++) acc2[t8] = (f32x4){0.f,0.f,0.f,0.f};
    int mrow = 16*w + c;
    int sw   = (mrow & 7) << 4;
    #pragma unroll
    for (int kk = 0; kk < 4; kk++){
        int ob = (mrow << 8) + (kk << 6) + (g16 << 3);
        FragU a2;
        a2.q2[0] = *(const uint2*)(lb + (ob ^ sw));
        a2.q2[1] = *(const uint2*)(lb + ((ob + 32) ^ sw));
        #pragma unroll
        for (int t8 = 0; t8 < 8; t8++){
            bf16x8 bf = *reinterpret_cast<const bf16x8*>(wp1 + (((kk*8 + t8)*64 + l) << 3));
            acc2[t8] = __builtin_amdgcn_mfma_f32_16x16x32_bf16(a2.v, bf, acc2[t8], 0, 0, 0);
        }
    }
    size_t zbase = (size_t)z*Nc*Nc*NHc;
    #pragma unroll
    for (int t8 = 0; t8 < 8; t8++){
        #pragma unroll
        for (int rg = 0; rg < 4; rg++){
            int m = 16*w + 4*g16 + rg;
            int b = b0 + m;
            unsigned short val = (unsigned short)cvtpk_bf16(ssp5_post(acc2[t8][rg]), 0.0f);
            h2[zbase + ((size_t)a*Nc + b)*NHc + 16*t8 + c] = val;
            if (b > a)
                h2[zbase + ((size_t)b*Nc + a)*NHc + 16*t8 + c] = val;
        }
    }
}

// ---------------------------------------------------------------------------
// MFMA gemm3: partial[s][z][a][i] = sum_{k' in slice s} h2[z,a,k']*gt[z,i,k']
// (K-order agnostic; both use k' = b*NH + chan).  grid = (64,2,Z); 4 waves.
template<int DOUT>
__global__ __launch_bounds__(256) void k_gemm3m(
    const unsigned short* __restrict__ h2, const unsigned short* __restrict__ gt,
    float* __restrict__ partial)
{
    __shared__ unsigned short Ash[64*256];     // 32 KB swizzled [r][k]
    __shared__ unsigned short Bsh[DOUT*256];   // 32/16 KB swizzled [c][k]
    int t = threadIdx.x;
    int w = t >> 6, l = t & 63;
    int g16 = l >> 4, c16 = l & 15;
    int s  = blockIdx.x;        // 0..63 k-slice (256 k' each)
    int at = blockIdx.y;        // 0..1
    int z  = blockIdx.z;
    int a0 = at*64;
    int k0 = s*256;

    {
        const unsigned short* src = h2 + ((size_t)(z*Nc + a0))*(Nc*NHc) + k0;
        #pragma unroll
        for (int it = 0; it < 8; it++){
            int idx = it*256 + t;
            int r = idx >> 5, c8 = idx & 31;
            uint4 v = *reinterpret_cast<const uint4*>(src + (size_t)r*(Nc*NHc) + c8*8);
            int byte = (r*512 + c8*16) ^ ((r & 7) << 4);
            *reinterpret_cast<uint4*>((char*)Ash + byte) = v;
        }
    }
    {
        const unsigned short* src = gt + ((size_t)z*DOUT)*(Nc*NHc) + k0;
        #pragma unroll
        for (int it = 0; it < DOUT/8; it++){
            int idx = it*256 + t;
            int r = idx >> 5, c8 = idx & 31;
            uint4 v = *reinterpret_cast<const uint4*>(src + (size_t)r*(Nc*NHc) + c8*8);
            int byte = (r*512 + c8*16) ^ ((r & 7) << 4);
            *reinterpret_cast<uint4*>((char*)Bsh + byte) = v;
        }
    }
    __syncthreads();

    constexpr int NT = DOUT/16;
    f32x4 acc[NT];
    #pragma unroll
    for (int nt = 0; nt < NT; nt++) acc[nt] = (f32x4){0.f,0.f,0.f,0.f};
    char* Ab = (char*)Ash; char* Bb = (char*)Bsh;
    int ar  = 16*w + c16;
    int asw = (ar & 7) << 4;
    #pragma unroll
    for (int ks = 0; ks < 8; ks++){
        FragU afr;
        int abyte = ar*512 + ks*64 + g16*8;
        afr.q2[0] = *(const uint2*)(Ab + (abyte ^ asw));
        afr.q2[1] = *(const uint2*)(Ab + ((abyte + 32) ^ asw));
        #pragma unroll
        for (int nt = 0; nt < NT; nt++){
            int br  = nt*16 + c16;
            int bsw = (br & 7) << 4;
            int bbyte = br*512 + ks*64 + g16*8;
            FragU bfr;
            bfr.q2[0] = *(const uint2*)(Bb + (bbyte ^ bsw));
            bfr.q2[1] = *(const uint2*)(Bb + ((bbyte + 32) ^ bsw));
            acc[nt] = __builtin_amdgcn_mfma_f32_16x16x32_bf16(afr.v, bfr.v, acc[nt], 0, 0, 0);
        }
    }
    #pragma unroll
    for (int nt = 0; nt < NT; nt++){
        #pragma unroll
        for (int rg = 0; rg < 4; rg++){
            int a = a0 + 16*w + 4*g16 + rg;
            int i = nt*16 + c16;
            partial[(((size_t)s*Zc + z)*Nc + a)*DOUT + i] = acc[nt][rg];
        }
    }
}

// ---------------------------------------------------------------------------
// Fused tail: layer-2 epilogue -> x1 -> bn1+leaky -> x2 -> bn2+leaky ->
// masked atomic sum into d_out (zeroed by k_init).  grid = N blocks.
__global__ __launch_bounds__(256) void k_tail(
    const float* __restrict__ part, const float* __restrict__ mask,
    const float* __restrict__ geo_pn,
    const float* __restrict__ e1w, const float* __restrict__ e1b,
    const float* __restrict__ g1, const float* __restrict__ b1,
    const float* __restrict__ e2w, const float* __restrict__ e2b,
    const float* __restrict__ g2, const float* __restrict__ b2,
    float* __restrict__ outp)
{
    int n = blockIdx.x;
    int t = threadIdx.x;
    __shared__ float feat[Zc][Cc];
    __shared__ float xln[Zc][Cc];
    __shared__ float r1[4], r2[4];

    {
        int z = t >> 6, i = t & 63;
        float s = 0.0f;
        #pragma unroll
        for (int sl = 0; sl < SLc; sl++)
            s += part[((size_t)sl*Zc*Nc + z*Nc + n)*MLPHc + i];
        float m = mask[z*Nc + n];
        feat[z][i] = sp5(s) * m;
        feat[z][MLPHc + i] = geo_pn[(z*Nc + n)*GEOc + i];
    }
    __syncthreads();

    int c  = t & 127;
    int zh = t >> 7;
    float x1v[2];
    float sum = 0.0f, sq = 0.0f;
    #pragma unroll
    for (int q = 0; q < 2; q++){
        int z = zh*2 + q;
        float s = e1b[c];
        for (int k = 0; k < Cc; k++) s = fmaf(feat[z][k], e1w[k*Cc + c], s);
        x1v[q] = s; sum += s; sq = fmaf(s, s, sq);
    }
    #pragma unroll
    for (int off = 32; off > 0; off >>= 1){
        sum += __shfl_down(sum, off);
        sq  += __shfl_down(sq,  off);
    }
    if ((t & 63) == 0){ r1[t >> 6] = sum; r2[t >> 6] = sq; }
    __syncthreads();
    {
        float tot  = r1[0]+r1[1]+r1[2]+r1[3];
        float totq = r2[0]+r2[1]+r2[2]+r2[3];
        float mu   = tot * (1.0f/512.0f);
        float var  = totq * (1.0f/512.0f) - mu*mu;
        float rstd = rsqrtf(var + 1e-5f);
        float ga = g1[n], be = b1[n];
        #pragma unroll
        for (int q = 0; q < 2; q++){
            float v = (x1v[q] - mu) * rstd * ga + be;
            xln[zh*2 + q][c] = v > 0.0f ? v : 0.2f*v;
        }
    }
    __syncthreads();

    float x2v[4];
    sum = 0.0f; sq = 0.0f;
    #pragma unroll
    for (int z = 0; z < Zc; z++){
        float s = e2b[t];
        for (int k = 0; k < Cc; k++) s = fmaf(xln[z][k], e2w[k*2*Cc + t], s);
        x2v[z] = s; sum += s; sq = fmaf(s, s, sq);
    }
    #pragma unroll
    for (int off = 32; off > 0; off >>= 1){
        sum += __shfl_down(sum, off);
        sq  += __shfl_down(sq,  off);
    }
    if ((t & 63) == 0){ r1[t >> 6] = sum; r2[t >> 6] = sq; }
    __syncthreads();
    {
        float tot  = r1[0]+r1[1]+r1[2]+r1[3];
        float totq = r2[0]+r2[1]+r2[2]+r2[3];
        float mu   = tot * (1.0f/1024.0f);
        float var  = totq * (1.0f/1024.0f) - mu*mu;
        float rstd = rsqrtf(var + 1e-5f);
        float ga = g2[n], be = b2[n];
        #pragma unroll
        for (int z = 0; z < Zc; z++){
            float v = (x2v[z] - mu) * rstd * ga + be;
            v = v > 0.0f ? v : 0.2f*v;
            atomicAdd(&outp[z*2*Cc + t], v * mask[z*Nc + n]);
        }
    }
}

// ---------------------------------------------------------------------------
extern "C" void kernel_launch(void* const* d_in, const int* in_sizes, int n_in,
                              void* d_out, int out_size, void* d_ws, size_t ws_size,
                              hipStream_t stream)
{
    const int*   features = (const int*)  d_in[0];
    const float* geom     = (const float*)d_in[1];
    const float* mask     = (const float*)d_in[2];
    const float* emb      = (const float*)d_in[3];
    const float* rw[3][3] = {
        {(const float*)d_in[4],  (const float*)d_in[5],  (const float*)d_in[6]},
        {(const float*)d_in[7],  (const float*)d_in[8],  (const float*)d_in[9]},
        {(const float*)d_in[10], (const float*)d_in[11], (const float*)d_in[12]}};
    const float* pw0 = (const float*)d_in[13]; const float* pb0 = (const float*)d_in[14];
    const float* w1a = (const float*)d_in[15]; const float* b1a = (const float*)d_in[16];
    const float* w1b = (const float*)d_in[17]; const float* b1b = (const float*)d_in[18];
    const float* w2a = (const float*)d_in[19]; const float* b2a = (const float*)d_in[20];
    const float* w2b = (const float*)d_in[21]; const float* b2b = (const float*)d_in[22];
    const float* e1w = (const float*)d_in[23]; const float* e1b = (const float*)d_in[24];
    const float* bn1g= (const float*)d_in[25]; const float* bn1b= (const float*)d_in[26];
    const float* e2w = (const float*)d_in[27]; const float* e2b = (const float*)d_in[28];
    const float* bn2g= (const float*)d_in[29]; const float* bn2b= (const float*)d_in[30];

    // workspace layout (float units from base)
    float* ws = (float*)d_ws;
    unsigned short* h2buf = (unsigned short*)ws;               // 3*Z*N*N*NH ushort
    unsigned short* gt    = (unsigned short*)(ws + 12582912);  // Z*64*16384 ushort
    float* part   = ws + 12582912 + 2097152;                   // SL*Z*N*64 = 2097152
    float* f0     = part + 2097152;                            // Z*N*EMB   = 8192
    float* geo_pn = f0 + 8192;                                 // Z*N*64    = 32768
    unsigned short* packs = (unsigned short*)(geo_pn + 32768); // 61440 ushorts
    (void)ws_size; (void)in_sizes; (void)n_in; (void)out_size;

    const size_t H2L = (size_t)Zc*Nc*Nc*NHc;                   // per-layer h2 elements

    // merged pointnet + packw + d_out zeroing
    k_init<<<369, 256, 0, stream>>>(geom, mask, pw0, pb0, w1a, b1a, w1b, b1b,
                                    w2a, b2a, w2b, b2b, features, emb,
                                    rw[0][0], rw[0][1], rw[1][0], rw[1][1],
                                    rw[2][0], rw[2][1],
                                    geo_pn, f0, packs, (float*)d_out);
    // all 3 layers' pair-MLPs, one launch (symmetry-halved, round-8 layout)
    k_pairmlp<<<dim3(Zc*Nc*Nc/64, 3), 256, 0, stream>>>(geom, packs, h2buf);

    // layer 0: din=16(EMB), dout=32
    k_gmat<16,32><<<dim3(Zc*Nc/8, (NHc*32)/256), 256, 0, stream>>>(f0, rw[0][2], gt);
    k_gemm3m<32><<<dim3(SLc,2,Zc), 256, 0, stream>>>(h2buf, gt, part);
    // layer 1: din=32, dout=32
    k_egmat<32,32><<<dim3(Zc*Nc/8, (NHc*32)/256), 256, 0, stream>>>(part, mask, rw[1][2], gt);
    k_gemm3m<32><<<dim3(SLc,2,Zc), 256, 0, stream>>>(h2buf + H2L, gt, part);
    // layer 2: din=32, dout=64
    k_egmat<32,64><<<dim3(Zc*Nc/8, (NHc*64)/256), 256, 0, stream>>>(part, mask, rw[2][2], gt);
    k_gemm3m<64><<<dim3(SLc,2,Zc), 256, 0, stream>>>(h2buf + 2*H2L, gt, part);

    // fused tail (epilogue2+x1+bn1+x2+bn2+masked atomic sum)
    k_tail<<<Nc, 256, 0, stream>>>(part, mask, geo_pn, e1w, e1b, bn1g, bn1b,
                                   e2w, e2b, bn2g, bn2b, (float*)d_out);
}